// Round 5
// baseline (666.125 us; speedup 1.0000x reference)
//
#include <hip/hip_runtime.h>
#include <cstdint>
#include <cstddef>

// ---------------- types ----------------
typedef __attribute__((ext_vector_type(8))) _Float16 half8;   // MFMA f16 A/B frag (4 VGPRs)
typedef __attribute__((ext_vector_type(4))) _Float16 half4;
typedef __attribute__((ext_vector_type(4))) float    floatx4; // MFMA C/D frag

static constexpr int B_ROWS = 16384;
static constexpr int IN_DIM = 256;
static constexpr int H_DIM  = 512;
static constexpr int NB     = 16;

__device__ __forceinline__ float fast_tanh(float x) {
  float ax = fabsf(x);
  float e  = __expf(2.0f * ax);             // e >= 1, inf-safe
  float t  = 1.0f - 2.0f / (e + 1.0f);
  return copysignf(t, x);
}

// async global->LDS, 16B per lane; LDS dest must be wave-uniform base + lane*16
__device__ __forceinline__ void gld16(const void* g, void* l) {
  __builtin_amdgcn_global_load_lds(
      (const __attribute__((address_space(1))) unsigned int*)g,
      (__attribute__((address_space(3))) unsigned int*)l, 16, 0, 0);
}

// ---------------- coeffs fp32 -> fp16, folding K_n = exp(-2 c_n^2); both arrays, one launch ----
__global__ __launch_bounds__(256) void cvt2_k(const float* __restrict__ s1, _Float16* __restrict__ d1, size_t n41,
                                              const float* __restrict__ s2, _Float16* __restrict__ d2, size_t n42) {
  size_t tot = n41 + n42;
  for (size_t i = (size_t)blockIdx.x * 256 + threadIdx.x; i < tot;
       i += (size_t)gridDim.x * 256) {
    const float4* sp; half4* dp; size_t j;
    if (i < n41) { sp = (const float4*)s1; dp = (half4*)d1; j = i; }
    else         { sp = (const float4*)s2; dp = (half4*)d2; j = i - n41; }
    float4 v = sp[j];
    int nb = (int)((j << 2) & 15);           // n-index of element 0 (NB=16 | everything)
    half4 r;
    float c0 = -2.f + (float)(nb + 0) * (4.f / 15.f);
    float c1 = -2.f + (float)(nb + 1) * (4.f / 15.f);
    float c2 = -2.f + (float)(nb + 2) * (4.f / 15.f);
    float c3 = -2.f + (float)(nb + 3) * (4.f / 15.f);
    r[0] = (_Float16)(v.x * __expf(-2.f * c0 * c0));
    r[1] = (_Float16)(v.y * __expf(-2.f * c1 * c1));
    r[2] = (_Float16)(v.z * __expf(-2.f * c2 * c2));
    r[3] = (_Float16)(v.w * __expf(-2.f * c3 * c3));
    dp[j] = r;
  }
}

// ---------------- per-column stats, two-pass (deterministic, no atomics) ----------------
__global__ __launch_bounds__(256) void stats_part_k(const float* __restrict__ X,
                                                    int rows, int cols,
                                                    double* __restrict__ ps,
                                                    double* __restrict__ ps2) {
  int c     = blockIdx.x * 64 + (threadIdx.x & 63);
  int chunk = threadIdx.x >> 6;
  int seg   = blockIdx.y;
  int rps   = rows / gridDim.y;
  int r0    = seg * rps;
  double s = 0.0, s2 = 0.0;
  for (int r = r0 + chunk; r < r0 + rps; r += 4) {
    float v = X[(size_t)r * cols + c];
    s += v; s2 += (double)v * (double)v;
  }
  __shared__ double Ls[256], Ls2[256];
  Ls[threadIdx.x] = s; Ls2[threadIdx.x] = s2;
  __syncthreads();
  if (chunk == 0) {
    int cl = threadIdx.x;
    s  = Ls[cl]  + Ls[cl + 64]  + Ls[cl + 128]  + Ls[cl + 192];
    s2 = Ls2[cl] + Ls2[cl + 64] + Ls2[cl + 128] + Ls2[cl + 192];
    ps [(size_t)seg * cols + c] = s;
    ps2[(size_t)seg * cols + c] = s2;
  }
}

__global__ void stats_final_k(const double* __restrict__ ps,
                              const double* __restrict__ ps2,
                              int segs, int cols, int rows,
                              float* __restrict__ mu, float* __restrict__ isd) {
  int c = blockIdx.x * blockDim.x + threadIdx.x;
  if (c >= cols) return;
  double s = 0.0, s2 = 0.0;
  for (int g = 0; g < segs; g++) { s += ps[(size_t)g * cols + c]; s2 += ps2[(size_t)g * cols + c]; }
  double mean = s / rows;
  double var  = (s2 - s * s / rows) / (rows - 1);   // ddof=1
  if (var < 0.0) var = 0.0;
  float sd = (float)sqrt(var);
  mu[c]  = (float)mean;
  isd[c] = 1.0f / (sd + 1e-6f);
}

// ---------------- fused normalize+expand+GEMM+tanh ----------------
// H[b, o] = tanh( sum_k basis(xn[b, k/16])_[k%16] * Cb[o, k] ),  K = C*16
// 128x256 macro-tile, 512 threads (8 waves 2x4), grid (B/128, 2) = 256 blocks = 1/CU.
// K-MAJOR LDS layout: 16B chunk (kseg,row) stored at kseg*ROWS+row -> frag b128 reads
// hit bank (row*4+j)%32: all 32 banks per quarter-wave phase, 2-way residual = free.
// LDS double-buffered, one barrier per K-step; expansion spread over all 512 threads.
__global__ __launch_bounds__(512) void kan_gemm_fused(const float* __restrict__ X,   // [B, C]
                                                      const float* __restrict__ mu,
                                                      const float* __restrict__ isd,
                                                      const _Float16* __restrict__ Bm, // [512, C*16]
                                                      float* __restrict__ Hout,        // [B, 512]
                                                      int C) {
  const int K = C << 4;
  const int steps = K >> 5;                 // BK = 32
  __shared__ __align__(16) _Float16 As[2][128 * 32];   // 16 KB; chunk = kseg*128 + row
  __shared__ __align__(16) _Float16 Bs[2][256 * 32];   // 32 KB; chunk = kseg*256 + row
  const int tid  = threadIdx.x;
  const int w = tid >> 6, lane = tid & 63;
  const int wm = w & 1, wn = w >> 1;        // 2 (rows) x 4 (cols) wave grid
  const int lrow = lane & 15, quad = lane >> 4;
  const int row0 = blockIdx.x * 128;
  const int col0 = blockIdx.y * 256;

  // ---- B staging: 1024 chunks/step; thread owns chunk c=tid (kseg=tid>>8, row=tid&255)
  //      and c=tid+512 (kseg+2, same row). Lane-contiguous per wave for gld16.
  const int b_row = tid & 255;
  const int b_ks  = tid >> 8;               // 0 or 1
  const _Float16* gB0 = Bm + (size_t)(col0 + b_row) * K + b_ks * 8;   // +16 halves for kseg+2

  // ---- A expansion: 512 chunks/step; thread owns chunk tid: kseg=tid>>7, row=tid&127.
  const int a_row = tid & 127;
  const int a_ks  = tid >> 7;               // 0..3
  const int a_h   = a_ks >> 1;              // which xn of the step (0/1)
  const int a_odd = a_ks & 1;               // n-offset 8 if set (wave-uniform)
  const float* xp = X + (size_t)(row0 + a_row) * C + a_h;   // xn(step k) = xp[2k]

  floatx4 acc[4][4] = {};

  auto expand_store = [&](float v, int ci, _Float16* dst) {
    float xn = fminf(fmaxf((v - mu[ci]) * isd[ci], -3.f), 3.f);
    float Wv = __expf(-2.f * xn * xn - 8.f * xn);
    float g  = __expf((16.f / 15.f) * xn);
    float p  = Wv;
    if (a_odd) { float g2 = g * g, g4 = g2 * g2; p *= g4 * g4; }   // start at n=8
    half8 h;
#pragma unroll
    for (int n = 0; n < 8; n++) { h[n] = (_Float16)p; p *= g; }
    *(half8*)dst = h;
  };

  // ---- prologue: fill buffer 0 ----
  gld16(gB0,      &Bs[0][(size_t)tid * 8]);
  gld16(gB0 + 16, &Bs[0][(size_t)(tid + 512) * 8]);
  expand_store(xp[0], a_h, &As[0][(size_t)tid * 8]);
  float xv_nxt = (steps > 1) ? xp[2] : 0.f;
  __syncthreads();

  // ---- main loop: one barrier per K-step ----
  for (int k = 0; k < steps; k++) {
    const int buf = k & 1, nb = buf ^ 1;
    if (k + 1 < steps) {
      gld16(gB0 + (size_t)(k + 1) * 32,      &Bs[nb][(size_t)tid * 8]);
      gld16(gB0 + (size_t)(k + 1) * 32 + 16, &Bs[nb][(size_t)(tid + 512) * 8]);
      expand_store(xv_nxt, 2 * (k + 1) + a_h, &As[nb][(size_t)tid * 8]);
      if (k + 2 < steps) xv_nxt = xp[2 * (k + 2)];
    }
    half8 af[4], bf[4];
#pragma unroll
    for (int t = 0; t < 4; t++) {
      af[t] = *(const half8*)&As[buf][quad * 1024 + (wm * 64 + t * 16 + lrow) * 8];
      bf[t] = *(const half8*)&Bs[buf][quad * 2048 + (wn * 64 + t * 16 + lrow) * 8];
    }
#pragma unroll
    for (int tm = 0; tm < 4; tm++)
#pragma unroll
      for (int tn = 0; tn < 4; tn++)
        acc[tm][tn] = __builtin_amdgcn_mfma_f32_16x16x32_f16(af[tm], bf[tn], acc[tm][tn], 0, 0, 0);
    __syncthreads();
  }

  // ---- epilogue: C/D layout col=lane&15, row=quad*4+reg; fused tanh ----
#pragma unroll
  for (int tm = 0; tm < 4; tm++) {
#pragma unroll
    for (int tn = 0; tn < 4; tn++) {
      int gcol = col0 + wn * 64 + tn * 16 + lrow;
#pragma unroll
      for (int r = 0; r < 4; r++) {
        int grow = row0 + wm * 64 + tm * 16 + quad * 4 + r;
        Hout[(size_t)grow * H_DIM + gcol] = fast_tanh(acc[tm][tn][r]);
      }
    }
  }
}

// ---------------- layer 3 (out dim 1) + skip, fp32, normalize fused ----------------
__global__ __launch_bounds__(256) void layer3_k(const float* __restrict__ H2,
                                                const float* __restrict__ mu,
                                                const float* __restrict__ isd,
                                                const float* __restrict__ C3,
                                                const float* __restrict__ X,
                                                const float* __restrict__ SW,
                                                const float* __restrict__ SB,
                                                float* __restrict__ OUT) {
  int w = threadIdx.x >> 6, lane = threadIdx.x & 63;
  float Kn[NB];
#pragma unroll
  for (int n = 0; n < NB; n++) {
    float c = -2.f + (float)n * (4.f / 15.f);
    Kn[n] = __expf(-2.f * c * c);
  }
  float sb0 = SB[0];
  int row_base = blockIdx.x * 16 + w * 4;
  for (int r = 0; r < 4; r++) {
    int row = row_base + r;
    float s = 0.f;
#pragma unroll
    for (int j = 0; j < 8; j++) {
      int i = lane + 64 * j;
      float hv = H2[(size_t)row * H_DIM + i];
      float xn = fminf(fmaxf((hv - mu[i]) * isd[i], -3.f), 3.f);
      float Wf = __expf(-2.f * xn * xn - 8.f * xn);
      float gf = __expf((16.f / 15.f) * xn);
      const floatx4* cp = (const floatx4*)(C3 + (size_t)i * NB);
      floatx4 c0 = cp[0], c1 = cp[1], c2 = cp[2], c3 = cp[3];
      float p = Wf;
#pragma unroll
      for (int n = 0; n < 4; n++) { s += p * Kn[n]      * c0[n]; p *= gf; }
#pragma unroll
      for (int n = 0; n < 4; n++) { s += p * Kn[n + 4]  * c1[n]; p *= gf; }
#pragma unroll
      for (int n = 0; n < 4; n++) { s += p * Kn[n + 8]  * c2[n]; p *= gf; }
#pragma unroll
      for (int n = 0; n < 4; n++) { s += p * Kn[n + 12] * c3[n]; p *= gf; }
    }
#pragma unroll
    for (int j = 0; j < 4; j++) {
      int i = lane + 64 * j;
      s += X[(size_t)row * IN_DIM + i] * SW[i];
    }
#pragma unroll
    for (int off = 32; off > 0; off >>= 1) s += __shfl_down(s, off);
    if (lane == 0) OUT[row] = s + sb0;
  }
}

// ---------------- launcher ----------------
extern "C" void kernel_launch(void* const* d_in, const int* in_sizes, int n_in,
                              void* d_out, int out_size, void* d_ws, size_t ws_size,
                              hipStream_t stream) {
  const float* x  = (const float*)d_in[0];   // [16384, 256]
  const float* c1 = (const float*)d_in[1];   // [512, 256, 16]
  const float* c2 = (const float*)d_in[2];   // [512, 512, 16]
  const float* c3 = (const float*)d_in[3];   // [1, 512, 16]
  const float* sw = (const float*)d_in[4];   // [1, 256]
  const float* sb = (const float*)d_in[5];   // [1]
  float* out = (float*)d_out;

  const int B = B_ROWS, IN = IN_DIM, H = H_DIM;

  char* ws = (char*)d_ws;
  size_t off = 0;
  auto alloc = [&](size_t bytes) -> void* {
    void* p = ws + off;
    off += (bytes + 255) & ~(size_t)255;
    return p;
  };
  _Float16* C1h = (_Float16*)alloc((size_t)H * IN * NB * 2);  //  4 MB
  _Float16* C2h = (_Float16*)alloc((size_t)H * H  * NB * 2);  //  8 MB
  float* H1 = (float*)alloc((size_t)B * H * 4);               // 32 MB
  float* H2 = (float*)alloc((size_t)B * H * 4);               // 32 MB
  double* ps  = (double*)alloc(32 * 512 * 8);
  double* ps2 = (double*)alloc(32 * 512 * 8);
  float* mu  = (float*)alloc(512 * 4);
  float* isd = (float*)alloc(512 * 4);

  // coeff conversion (K_n folded in), single launch
  cvt2_k<<<1024, 256, 0, stream>>>(c1, C1h, (size_t)H * IN * NB / 4,
                                   c2, C2h, (size_t)H * H * NB / 4);

  // ---- layer 1 (C=256, K=4096) ----
  stats_part_k<<<dim3(IN / 64, 32), 256, 0, stream>>>(x, B, IN, ps, ps2);
  stats_final_k<<<1, 256, 0, stream>>>(ps, ps2, 32, IN, B, mu, isd);
  kan_gemm_fused<<<dim3(B / 128, 2), 512, 0, stream>>>(x, mu, isd, C1h, H1, IN);

  // ---- layer 2 (C=512, K=8192, single dispatch) ----
  stats_part_k<<<dim3(H / 64, 32), 256, 0, stream>>>(H1, B, H, ps, ps2);
  stats_final_k<<<2, 256, 0, stream>>>(ps, ps2, 32, H, B, mu, isd);
  kan_gemm_fused<<<dim3(B / 128, 2), 512, 0, stream>>>(H1, mu, isd, C2h, H2, H);

  // ---- layer 3 + skip (normalize fused) ----
  stats_part_k<<<dim3(H / 64, 32), 256, 0, stream>>>(H2, B, H, ps, ps2);
  stats_final_k<<<2, 256, 0, stream>>>(ps, ps2, 32, H, B, mu, isd);
  layer3_k<<<B / 16, 256, 0, stream>>>(H2, mu, isd, c3, x, sw, sb, out);
}

// Round 6
// 522.907 us; speedup vs baseline: 1.2739x; 1.2739x over previous
//
#include <hip/hip_runtime.h>
#include <cstdint>
#include <cstddef>

// ---------------- types ----------------
typedef __attribute__((ext_vector_type(8))) _Float16 half8;   // MFMA f16 A/B frag (4 VGPRs)
typedef __attribute__((ext_vector_type(4))) _Float16 half4;
typedef __attribute__((ext_vector_type(4))) float    floatx4; // MFMA C/D frag

static constexpr int B_ROWS = 16384;
static constexpr int IN_DIM = 256;
static constexpr int H_DIM  = 512;
static constexpr int NB     = 16;

__device__ __forceinline__ float fast_tanh(float x) {
  float ax = fabsf(x);
  float e  = __expf(2.0f * ax);             // e >= 1, inf-safe
  float t  = 1.0f - 2.0f / (e + 1.0f);
  return copysignf(t, x);
}

// async global->LDS, 16B per lane; LDS dest must be wave-uniform base + lane*16
__device__ __forceinline__ void gld16(const void* g, void* l) {
  __builtin_amdgcn_global_load_lds(
      (const __attribute__((address_space(1))) unsigned int*)g,
      (__attribute__((address_space(3))) unsigned int*)l, 16, 0, 0);
}

// ---------------- coeffs fp32 -> fp16, folding K_n = exp(-2 c_n^2); both arrays, one launch ----
__global__ __launch_bounds__(256) void cvt2_k(const float* __restrict__ s1, _Float16* __restrict__ d1, size_t n41,
                                              const float* __restrict__ s2, _Float16* __restrict__ d2, size_t n42) {
  size_t tot = n41 + n42;
  for (size_t i = (size_t)blockIdx.x * 256 + threadIdx.x; i < tot;
       i += (size_t)gridDim.x * 256) {
    const float4* sp; half4* dp; size_t j;
    if (i < n41) { sp = (const float4*)s1; dp = (half4*)d1; j = i; }
    else         { sp = (const float4*)s2; dp = (half4*)d2; j = i - n41; }
    float4 v = sp[j];
    int nb = (int)((j << 2) & 15);           // n-index of element 0 (NB=16 | everything)
    half4 r;
    float c0 = -2.f + (float)(nb + 0) * (4.f / 15.f);
    float c1 = -2.f + (float)(nb + 1) * (4.f / 15.f);
    float c2 = -2.f + (float)(nb + 2) * (4.f / 15.f);
    float c3 = -2.f + (float)(nb + 3) * (4.f / 15.f);
    r[0] = (_Float16)(v.x * __expf(-2.f * c0 * c0));
    r[1] = (_Float16)(v.y * __expf(-2.f * c1 * c1));
    r[2] = (_Float16)(v.z * __expf(-2.f * c2 * c2));
    r[3] = (_Float16)(v.w * __expf(-2.f * c3 * c3));
    dp[j] = r;
  }
}

// ---------------- per-column stats, two-pass (deterministic, no atomics) ----------------
__global__ __launch_bounds__(256) void stats_part_k(const float* __restrict__ X,
                                                    int rows, int cols,
                                                    double* __restrict__ ps,
                                                    double* __restrict__ ps2) {
  int c     = blockIdx.x * 64 + (threadIdx.x & 63);
  int chunk = threadIdx.x >> 6;
  int seg   = blockIdx.y;
  int rps   = rows / gridDim.y;
  int r0    = seg * rps;
  double s = 0.0, s2 = 0.0;
  for (int r = r0 + chunk; r < r0 + rps; r += 4) {
    float v = X[(size_t)r * cols + c];
    s += v; s2 += (double)v * (double)v;
  }
  __shared__ double Ls[256], Ls2[256];
  Ls[threadIdx.x] = s; Ls2[threadIdx.x] = s2;
  __syncthreads();
  if (chunk == 0) {
    int cl = threadIdx.x;
    s  = Ls[cl]  + Ls[cl + 64]  + Ls[cl + 128]  + Ls[cl + 192];
    s2 = Ls2[cl] + Ls2[cl + 64] + Ls2[cl + 128] + Ls2[cl + 192];
    ps [(size_t)seg * cols + c] = s;
    ps2[(size_t)seg * cols + c] = s2;
  }
}

__global__ void stats_final_k(const double* __restrict__ ps,
                              const double* __restrict__ ps2,
                              int segs, int cols, int rows,
                              float* __restrict__ mu, float* __restrict__ isd) {
  int c = blockIdx.x * blockDim.x + threadIdx.x;
  if (c >= cols) return;
  double s = 0.0, s2 = 0.0;
  for (int g = 0; g < segs; g++) { s += ps[(size_t)g * cols + c]; s2 += ps2[(size_t)g * cols + c]; }
  double mean = s / rows;
  double var  = (s2 - s * s / rows) / (rows - 1);   // ddof=1
  if (var < 0.0) var = 0.0;
  float sd = (float)sqrt(var);
  mu[c]  = (float)mean;
  isd[c] = 1.0f / (sd + 1e-6f);
}

// ---------------- fused normalize+expand+GEMM+tanh ----------------
// H[b, o] = tanh( sum_k basis(xn[b, k/16])_[k%16] * Cb[o, k] ),  K = C*16
// 128x256 macro-tile, 512 threads (8 waves 2x4), grid (B/128, 2) = 256 blocks = 1/CU.
// A (generated in-kernel): K-major LDS, conflict-free (measured 0 in R5).
// B (DMA'd): XOR-swizzled layout — LDS chunk (row, sl) holds global seg = sl ^ ((row>>1)&3).
//   * staging: each 4-lane group covers one aligned 64B row-run (perm inside) -> coalesced (R4-level)
//   * frag read: bank-group = 4(row&1) + (quad^((row>>1)&3)) -> 8 groups x 2-way per phase = free
__global__ __launch_bounds__(512) void kan_gemm_fused(const float* __restrict__ X,   // [B, C]
                                                      const float* __restrict__ mu,
                                                      const float* __restrict__ isd,
                                                      const _Float16* __restrict__ Bm, // [512, C*16]
                                                      float* __restrict__ Hout,        // [B, 512]
                                                      int C) {
  const int K = C << 4;
  const int steps = K >> 5;                 // BK = 32
  __shared__ __align__(16) _Float16 As[2][128 * 32];   // 16 KB; chunk = kseg*128 + row
  __shared__ __align__(16) _Float16 Bs[2][256 * 32];   // 32 KB; chunk = row*4 + swizzled seg
  const int tid  = threadIdx.x;
  const int w = tid >> 6, lane = tid & 63;
  const int wm = w & 1, wn = w >> 1;        // 2 (rows) x 4 (cols) wave grid
  const int lrow = lane & 15, quad = lane >> 4;
  const int row0 = blockIdx.x * 128;
  const int col0 = blockIdx.y * 256;

  // ---- B staging: LDS chunk c holds global (row=c>>2, seg=(c&3)^((row>>1)&3)).
  //      Thread's chunks: c1 = w*64+lane (rows w*16..+15), c2 = c1+512 (rows +128).
  const int s_row1 = w * 16 + (lane >> 2);
  const int s_row2 = s_row1 + 128;
  const int s_sl   = lane & 3;
  const int s_seg1 = s_sl ^ ((s_row1 >> 1) & 3);
  const int s_seg2 = s_sl ^ ((s_row2 >> 1) & 3);
  const _Float16* gB1 = Bm + (size_t)(col0 + s_row1) * K + s_seg1 * 8;
  const _Float16* gB2 = Bm + (size_t)(col0 + s_row2) * K + s_seg2 * 8;

  // ---- A expansion: 512 chunks/step; thread owns chunk tid: kseg=tid>>7, row=tid&127.
  const int a_row = tid & 127;
  const int a_ks  = tid >> 7;               // 0..3
  const int a_h   = a_ks >> 1;              // which xn of the step (0/1)
  const int a_odd = a_ks & 1;               // n-offset 8 if set (wave-uniform)
  const float* xp = X + (size_t)(row0 + a_row) * C + a_h;   // xn(step k) = xp[2k]

  floatx4 acc[4][4] = {};

  auto expand_store = [&](float v, int ci, _Float16* dst) {
    float xn = fminf(fmaxf((v - mu[ci]) * isd[ci], -3.f), 3.f);
    float Wv = __expf(-2.f * xn * xn - 8.f * xn);
    float g  = __expf((16.f / 15.f) * xn);
    float p  = Wv;
    if (a_odd) { float g2 = g * g, g4 = g2 * g2; p *= g4 * g4; }   // start at n=8
    half8 h;
#pragma unroll
    for (int n = 0; n < 8; n++) { h[n] = (_Float16)p; p *= g; }
    *(half8*)dst = h;
  };

  // ---- prologue: fill buffer 0 ----
  gld16(gB1, &Bs[0][(size_t)tid * 8]);
  gld16(gB2, &Bs[0][(size_t)(tid + 512) * 8]);
  expand_store(xp[0], a_h, &As[0][(size_t)tid * 8]);
  float xv_nxt = (steps > 1) ? xp[2] : 0.f;
  __syncthreads();

  // ---- main loop: one barrier per K-step; DMA for k+1 issued before MFMA of k ----
  for (int k = 0; k < steps; k++) {
    const int buf = k & 1, nb = buf ^ 1;
    if (k + 1 < steps) {
      gld16(gB1 + (size_t)(k + 1) * 32, &Bs[nb][(size_t)tid * 8]);
      gld16(gB2 + (size_t)(k + 1) * 32, &Bs[nb][(size_t)(tid + 512) * 8]);
      expand_store(xv_nxt, 2 * (k + 1) + a_h, &As[nb][(size_t)tid * 8]);
      if (k + 2 < steps) xv_nxt = xp[2 * (k + 2)];
    }
    half8 af[4], bf[4];
#pragma unroll
    for (int t = 0; t < 4; t++) {
      int arow = wm * 64 + t * 16 + lrow;
      af[t] = *(const half8*)&As[buf][(quad * 128 + arow) * 8];
      int brow = wn * 64 + t * 16 + lrow;
      int bchunk = brow * 4 + (quad ^ ((brow >> 1) & 3));
      bf[t] = *(const half8*)&Bs[buf][bchunk * 8];
    }
#pragma unroll
    for (int tm = 0; tm < 4; tm++)
#pragma unroll
      for (int tn = 0; tn < 4; tn++)
        acc[tm][tn] = __builtin_amdgcn_mfma_f32_16x16x32_f16(af[tm], bf[tn], acc[tm][tn], 0, 0, 0);
    __syncthreads();
  }

  // ---- epilogue: C/D layout col=lane&15, row=quad*4+reg; fused tanh ----
#pragma unroll
  for (int tm = 0; tm < 4; tm++) {
#pragma unroll
    for (int tn = 0; tn < 4; tn++) {
      int gcol = col0 + wn * 64 + tn * 16 + lrow;
#pragma unroll
      for (int r = 0; r < 4; r++) {
        int grow = row0 + wm * 64 + tm * 16 + quad * 4 + r;
        Hout[(size_t)grow * H_DIM + gcol] = fast_tanh(acc[tm][tn][r]);
      }
    }
  }
}

// ---------------- layer 3 (out dim 1) + skip, fp32, normalize fused ----------------
__global__ __launch_bounds__(256) void layer3_k(const float* __restrict__ H2,
                                                const float* __restrict__ mu,
                                                const float* __restrict__ isd,
                                                const float* __restrict__ C3,
                                                const float* __restrict__ X,
                                                const float* __restrict__ SW,
                                                const float* __restrict__ SB,
                                                float* __restrict__ OUT) {
  int w = threadIdx.x >> 6, lane = threadIdx.x & 63;
  float Kn[NB];
#pragma unroll
  for (int n = 0; n < NB; n++) {
    float c = -2.f + (float)n * (4.f / 15.f);
    Kn[n] = __expf(-2.f * c * c);
  }
  float sb0 = SB[0];
  int row_base = blockIdx.x * 16 + w * 4;
  for (int r = 0; r < 4; r++) {
    int row = row_base + r;
    float s = 0.f;
#pragma unroll
    for (int j = 0; j < 8; j++) {
      int i = lane + 64 * j;
      float hv = H2[(size_t)row * H_DIM + i];
      float xn = fminf(fmaxf((hv - mu[i]) * isd[i], -3.f), 3.f);
      float Wf = __expf(-2.f * xn * xn - 8.f * xn);
      float gf = __expf((16.f / 15.f) * xn);
      const floatx4* cp = (const floatx4*)(C3 + (size_t)i * NB);
      floatx4 c0 = cp[0], c1 = cp[1], c2 = cp[2], c3 = cp[3];
      float p = Wf;
#pragma unroll
      for (int n = 0; n < 4; n++) { s += p * Kn[n]      * c0[n]; p *= gf; }
#pragma unroll
      for (int n = 0; n < 4; n++) { s += p * Kn[n + 4]  * c1[n]; p *= gf; }
#pragma unroll
      for (int n = 0; n < 4; n++) { s += p * Kn[n + 8]  * c2[n]; p *= gf; }
#pragma unroll
      for (int n = 0; n < 4; n++) { s += p * Kn[n + 12] * c3[n]; p *= gf; }
    }
#pragma unroll
    for (int j = 0; j < 4; j++) {
      int i = lane + 64 * j;
      s += X[(size_t)row * IN_DIM + i] * SW[i];
    }
#pragma unroll
    for (int off = 32; off > 0; off >>= 1) s += __shfl_down(s, off);
    if (lane == 0) OUT[row] = s + sb0;
  }
}

// ---------------- launcher ----------------
extern "C" void kernel_launch(void* const* d_in, const int* in_sizes, int n_in,
                              void* d_out, int out_size, void* d_ws, size_t ws_size,
                              hipStream_t stream) {
  const float* x  = (const float*)d_in[0];   // [16384, 256]
  const float* c1 = (const float*)d_in[1];   // [512, 256, 16]
  const float* c2 = (const float*)d_in[2];   // [512, 512, 16]
  const float* c3 = (const float*)d_in[3];   // [1, 512, 16]
  const float* sw = (const float*)d_in[4];   // [1, 256]
  const float* sb = (const float*)d_in[5];   // [1]
  float* out = (float*)d_out;

  const int B = B_ROWS, IN = IN_DIM, H = H_DIM;

  char* ws = (char*)d_ws;
  size_t off = 0;
  auto alloc = [&](size_t bytes) -> void* {
    void* p = ws + off;
    off += (bytes + 255) & ~(size_t)255;
    return p;
  };
  _Float16* C1h = (_Float16*)alloc((size_t)H * IN * NB * 2);  //  4 MB
  _Float16* C2h = (_Float16*)alloc((size_t)H * H  * NB * 2);  //  8 MB
  float* H1 = (float*)alloc((size_t)B * H * 4);               // 32 MB
  float* H2 = (float*)alloc((size_t)B * H * 4);               // 32 MB
  double* ps  = (double*)alloc(32 * 512 * 8);
  double* ps2 = (double*)alloc(32 * 512 * 8);
  float* mu  = (float*)alloc(512 * 4);
  float* isd = (float*)alloc(512 * 4);

  // coeff conversion (K_n folded in), single launch
  cvt2_k<<<1024, 256, 0, stream>>>(c1, C1h, (size_t)H * IN * NB / 4,
                                   c2, C2h, (size_t)H * H * NB / 4);

  // ---- layer 1 (C=256, K=4096) ----
  stats_part_k<<<dim3(IN / 64, 32), 256, 0, stream>>>(x, B, IN, ps, ps2);
  stats_final_k<<<1, 256, 0, stream>>>(ps, ps2, 32, IN, B, mu, isd);
  kan_gemm_fused<<<dim3(B / 128, 2), 512, 0, stream>>>(x, mu, isd, C1h, H1, IN);

  // ---- layer 2 (C=512, K=8192, single dispatch) ----
  stats_part_k<<<dim3(H / 64, 32), 256, 0, stream>>>(H1, B, H, ps, ps2);
  stats_final_k<<<2, 256, 0, stream>>>(ps, ps2, 32, H, B, mu, isd);
  kan_gemm_fused<<<dim3(B / 128, 2), 512, 0, stream>>>(H1, mu, isd, C2h, H2, H);

  // ---- layer 3 + skip (normalize fused) ----
  stats_part_k<<<dim3(H / 64, 32), 256, 0, stream>>>(H2, B, H, ps, ps2);
  stats_final_k<<<2, 256, 0, stream>>>(ps, ps2, 32, H, B, mu, isd);
  layer3_k<<<B / 16, 256, 0, stream>>>(H2, mu, isd, c3, x, sw, sb, out);
}

// Round 7
// 494.331 us; speedup vs baseline: 1.3475x; 1.0578x over previous
//
#include <hip/hip_runtime.h>
#include <cstdint>
#include <cstddef>

// ---------------- types ----------------
typedef __attribute__((ext_vector_type(8))) _Float16 half8;   // MFMA f16 A/B frag (4 VGPRs)
typedef __attribute__((ext_vector_type(4))) _Float16 half4;
typedef __attribute__((ext_vector_type(4))) float    floatx4; // MFMA C/D frag

static constexpr int B_ROWS = 16384;
static constexpr int IN_DIM = 256;
static constexpr int H_DIM  = 512;
static constexpr int NB     = 16;

__device__ __forceinline__ float fast_tanh(float x) {
  float ax = fabsf(x);
  float e  = __expf(2.0f * ax);             // e >= 1, inf-safe
  float t  = 1.0f - 2.0f / (e + 1.0f);
  return copysignf(t, x);
}

// async global->LDS, 16B per lane; LDS dest must be wave-uniform base + lane*16
__device__ __forceinline__ void gld16(const void* g, void* l) {
  __builtin_amdgcn_global_load_lds(
      (const __attribute__((address_space(1))) unsigned int*)g,
      (__attribute__((address_space(3))) unsigned int*)l, 16, 0, 0);
}

// ---------------- prep: x column-stats partials (blocks 0..127) + coeff cvt (blocks 128+) ----
// cvt folds K_n = exp(-2 c_n^2) into the fp16 coeffs.
__global__ __launch_bounds__(256) void prep_k(const float* __restrict__ c1, _Float16* __restrict__ d1, size_t n41,
                                              const float* __restrict__ c2, _Float16* __restrict__ d2, size_t n42,
                                              const float* __restrict__ X,
                                              float* __restrict__ ps, float* __restrict__ ps2) {
  const int bx = blockIdx.x;
  if (bx < 128) {
    // ---- stats on X: cols=256 (4 col-groups of 64), 32 row-segs of 512 ----
    int c     = (bx & 3) * 64 + (threadIdx.x & 63);
    int chunk = threadIdx.x >> 6;
    int seg   = bx >> 2;
    int r0    = seg * 512;
    double s = 0.0, s2 = 0.0;
    for (int r = r0 + chunk; r < r0 + 512; r += 4) {
      float v = X[(size_t)r * IN_DIM + c];
      s += v; s2 += (double)v * (double)v;
    }
    __shared__ float Ls[256], Ls2[256];
    Ls[threadIdx.x] = (float)s; Ls2[threadIdx.x] = (float)s2;
    __syncthreads();
    if (chunk == 0) {
      int cl = threadIdx.x;
      float a  = Ls[cl]  + Ls[cl + 64]  + Ls[cl + 128]  + Ls[cl + 192];
      float b  = Ls2[cl] + Ls2[cl + 64] + Ls2[cl + 128] + Ls2[cl + 192];
      ps [(size_t)seg * IN_DIM + c] = a;
      ps2[(size_t)seg * IN_DIM + c] = b;
    }
  } else {
    // ---- coeff conversion, grid-stride over remaining blocks ----
    size_t tot = n41 + n42;
    int nb_blocks = gridDim.x - 128;
    for (size_t i = (size_t)(bx - 128) * 256 + threadIdx.x; i < tot;
         i += (size_t)nb_blocks * 256) {
      const float4* sp; half4* dp; size_t j;
      if (i < n41) { sp = (const float4*)c1; dp = (half4*)d1; j = i; }
      else         { sp = (const float4*)c2; dp = (half4*)d2; j = i - n41; }
      float4 v = sp[j];
      int nb = (int)((j << 2) & 15);
      half4 r;
      float e0 = -2.f + (float)(nb + 0) * (4.f / 15.f);
      float e1 = -2.f + (float)(nb + 1) * (4.f / 15.f);
      float e2 = -2.f + (float)(nb + 2) * (4.f / 15.f);
      float e3 = -2.f + (float)(nb + 3) * (4.f / 15.f);
      r[0] = (_Float16)(v.x * __expf(-2.f * e0 * e0));
      r[1] = (_Float16)(v.y * __expf(-2.f * e1 * e1));
      r[2] = (_Float16)(v.z * __expf(-2.f * e2 * e2));
      r[3] = (_Float16)(v.w * __expf(-2.f * e3 * e3));
      dp[j] = r;
    }
  }
}

// ---------------- stats finalize (float partials) ----------------
__global__ void stats_final_k(const float* __restrict__ ps,
                              const float* __restrict__ ps2,
                              int segs, int cols, int rows,
                              float* __restrict__ mu, float* __restrict__ isd) {
  int c = blockIdx.x * blockDim.x + threadIdx.x;
  if (c >= cols) return;
  double s = 0.0, s2 = 0.0;
  for (int g = 0; g < segs; g++) { s += ps[(size_t)g * cols + c]; s2 += ps2[(size_t)g * cols + c]; }
  double mean = s / rows;
  double var  = (s2 - s * s / rows) / (rows - 1);   // ddof=1
  if (var < 0.0) var = 0.0;
  float sd = (float)sqrt(var);
  mu[c]  = (float)mean;
  isd[c] = 1.0f / (sd + 1e-6f);
}

// ---------------- fused normalize+expand+GEMM+tanh + column-stats partials ----------------
// H[b, o] = tanh( sum_k basis(xn[b, k/16])_[k%16] * Cb[o, k] ),  K = C*16
// 128x128 tile, 256 threads (4 waves 2x2), grid (B/128, 4) = 512 blocks = 2 blocks/CU:
// while one block drains vmcnt at its barrier, the other computes (the R6 1-block/CU
// structure serialized drain+compute at ~2016 cyc/step).
// A: K-major LDS (0-conflict, R5-measured). B: XOR swizzle seg = sl ^ ((row>>1)&3)
// (coalesced DMA + 0-conflict frag reads, R6-measured).
// Epilogue: fused per-block column sums of h and h^2 -> psum/psum2 (f32) for next layer's stats.
__global__ __launch_bounds__(256, 2) void kan_gemm_fused(const float* __restrict__ X,   // [B, C]
                                                         const float* __restrict__ mu,
                                                         const float* __restrict__ isd,
                                                         const _Float16* __restrict__ Bm, // [512, C*16]
                                                         float* __restrict__ Hout,        // [B, 512]
                                                         float* __restrict__ psum,        // [128, 512]
                                                         float* __restrict__ psum2,       // [128, 512]
                                                         int C) {
  const int K = C << 4;
  const int steps = K >> 5;                 // BK = 32
  __shared__ __align__(16) _Float16 As[2][128 * 32];   // 16 KB; chunk = kseg*128 + row
  __shared__ __align__(16) _Float16 Bs[2][128 * 32];   // 16 KB; chunk = row*4 + swizzled seg
  __shared__ float Rs1[2][128], Rs2[2][128];           //  2 KB epilogue reduction
  const int tid  = threadIdx.x;
  const int w = tid >> 6, lane = tid & 63;
  const int wm = w & 1, wn = w >> 1;        // 2x2 wave grid
  const int lrow = lane & 15, quad = lane >> 4;
  const int row0 = blockIdx.x * 128;
  const int col0 = blockIdx.y * 128;

  // ---- B staging: LDS chunk c = row*4+sl holds global seg = sl ^ ((row>>1)&3).
  //      Thread's chunks: c1 = tid (rows 0..63), c2 = tid+256 (rows 64..127).
  const int s_row1 = w * 16 + (lane >> 2);
  const int s_row2 = s_row1 + 64;
  const int s_sl   = lane & 3;
  const int s_seg1 = s_sl ^ ((s_row1 >> 1) & 3);
  const int s_seg2 = s_sl ^ ((s_row2 >> 1) & 3);
  const _Float16* gB1 = Bm + (size_t)(col0 + s_row1) * K + s_seg1 * 8;
  const _Float16* gB2 = Bm + (size_t)(col0 + s_row2) * K + s_seg2 * 8;

  // ---- A expansion: thread -> row = tid>>1, xn-half eh = tid&1; writes ksegs 2eh, 2eh+1.
  const int erow = tid >> 1, eh = tid & 1;
  const float* xp = X + (size_t)(row0 + erow) * C + eh;   // xn(step k) = xp[2k]

  floatx4 acc[4][4] = {};

  auto expand_store = [&](float v, int ci, int bufi) {
    float xn = fminf(fmaxf((v - mu[ci]) * isd[ci], -3.f), 3.f);
    float Wv = __expf(-2.f * xn * xn - 8.f * xn);
    float g  = __expf((16.f / 15.f) * xn);
    half8 h0, h1;
    float p = Wv;
#pragma unroll
    for (int n = 0; n < 8; n++) { h0[n] = (_Float16)p; p *= g; }
#pragma unroll
    for (int n = 0; n < 8; n++) { h1[n] = (_Float16)p; p *= g; }
    *(half8*)&As[bufi][(size_t)((2 * eh)     * 128 + erow) * 8] = h0;
    *(half8*)&As[bufi][(size_t)((2 * eh + 1) * 128 + erow) * 8] = h1;
  };

  // ---- prologue: fill buffer 0 ----
  gld16(gB1, &Bs[0][(size_t)tid * 8]);
  gld16(gB2, &Bs[0][(size_t)(tid + 256) * 8]);
  expand_store(xp[0], eh, 0);
  float xv = (steps > 1) ? xp[2] : 0.f;
  __syncthreads();

  // ---- main loop: one barrier per K-step; DMA for k+1 issued before MFMA of k ----
  for (int k = 0; k < steps; k++) {
    const int buf = k & 1, nb = buf ^ 1;
    if (k + 1 < steps) {
      gld16(gB1 + (size_t)(k + 1) * 32, &Bs[nb][(size_t)tid * 8]);
      gld16(gB2 + (size_t)(k + 1) * 32, &Bs[nb][(size_t)(tid + 256) * 8]);
      expand_store(xv, 2 * (k + 1) + eh, nb);
      if (k + 2 < steps) xv = xp[2 * (k + 2)];
    }
    half8 af[4], bf[4];
#pragma unroll
    for (int t = 0; t < 4; t++) {
      int arow = wm * 64 + t * 16 + lrow;
      af[t] = *(const half8*)&As[buf][(quad * 128 + arow) * 8];
      int brow = wn * 64 + t * 16 + lrow;
      int bchunk = brow * 4 + (quad ^ ((brow >> 1) & 3));
      bf[t] = *(const half8*)&Bs[buf][bchunk * 8];
    }
#pragma unroll
    for (int tm = 0; tm < 4; tm++)
#pragma unroll
      for (int tn = 0; tn < 4; tn++)
        acc[tm][tn] = __builtin_amdgcn_mfma_f32_16x16x32_f16(af[tm], bf[tn], acc[tm][tn], 0, 0, 0);
    __syncthreads();
  }

  // ---- epilogue: C/D layout col=lane&15, row=quad*4+reg; fused tanh + column partial sums ----
  float s1[4] = {0.f, 0.f, 0.f, 0.f}, s2v[4] = {0.f, 0.f, 0.f, 0.f};
#pragma unroll
  for (int tm = 0; tm < 4; tm++) {
#pragma unroll
    for (int tn = 0; tn < 4; tn++) {
      int gcol = col0 + wn * 64 + tn * 16 + lrow;
#pragma unroll
      for (int r = 0; r < 4; r++) {
        int grow = row0 + wm * 64 + tm * 16 + quad * 4 + r;
        float v = fast_tanh(acc[tm][tn][r]);
        Hout[(size_t)grow * H_DIM + gcol] = v;
        s1[tn] += v; s2v[tn] += v * v;
      }
    }
  }
  // reduce over quad (rows within the wave's 64-row span)
#pragma unroll
  for (int tn = 0; tn < 4; tn++) {
    s1[tn]  += __shfl_xor(s1[tn], 16);  s1[tn]  += __shfl_xor(s1[tn], 32);
    s2v[tn] += __shfl_xor(s2v[tn], 16); s2v[tn] += __shfl_xor(s2v[tn], 32);
  }
  if (quad == 0) {
#pragma unroll
    for (int tn = 0; tn < 4; tn++) {
      Rs1[wm][wn * 64 + tn * 16 + lrow] = s1[tn];
      Rs2[wm][wn * 64 + tn * 16 + lrow] = s2v[tn];
    }
  }
  __syncthreads();
  if (tid < 128) {
    psum [(size_t)blockIdx.x * H_DIM + col0 + tid] = Rs1[0][tid] + Rs1[1][tid];
    psum2[(size_t)blockIdx.x * H_DIM + col0 + tid] = Rs2[0][tid] + Rs2[1][tid];
  }
}

// ---------------- layer 3 (out dim 1) + skip, fp32, normalize fused ----------------
__global__ __launch_bounds__(256) void layer3_k(const float* __restrict__ H2,
                                                const float* __restrict__ mu,
                                                const float* __restrict__ isd,
                                                const float* __restrict__ C3,
                                                const float* __restrict__ X,
                                                const float* __restrict__ SW,
                                                const float* __restrict__ SB,
                                                float* __restrict__ OUT) {
  int w = threadIdx.x >> 6, lane = threadIdx.x & 63;
  float Kn[NB];
#pragma unroll
  for (int n = 0; n < NB; n++) {
    float c = -2.f + (float)n * (4.f / 15.f);
    Kn[n] = __expf(-2.f * c * c);
  }
  float sb0 = SB[0];
  int row_base = blockIdx.x * 16 + w * 4;
  for (int r = 0; r < 4; r++) {
    int row = row_base + r;
    float s = 0.f;
#pragma unroll
    for (int j = 0; j < 8; j++) {
      int i = lane + 64 * j;
      float hv = H2[(size_t)row * H_DIM + i];
      float xn = fminf(fmaxf((hv - mu[i]) * isd[i], -3.f), 3.f);
      float Wf = __expf(-2.f * xn * xn - 8.f * xn);
      float gf = __expf((16.f / 15.f) * xn);
      const floatx4* cp = (const floatx4*)(C3 + (size_t)i * NB);
      floatx4 c0 = cp[0], c1 = cp[1], c2 = cp[2], c3 = cp[3];
      float p = Wf;
#pragma unroll
      for (int n = 0; n < 4; n++) { s += p * Kn[n]      * c0[n]; p *= gf; }
#pragma unroll
      for (int n = 0; n < 4; n++) { s += p * Kn[n + 4]  * c1[n]; p *= gf; }
#pragma unroll
      for (int n = 0; n < 4; n++) { s += p * Kn[n + 8]  * c2[n]; p *= gf; }
#pragma unroll
      for (int n = 0; n < 4; n++) { s += p * Kn[n + 12] * c3[n]; p *= gf; }
    }
#pragma unroll
    for (int j = 0; j < 4; j++) {
      int i = lane + 64 * j;
      s += X[(size_t)row * IN_DIM + i] * SW[i];
    }
#pragma unroll
    for (int off = 32; off > 0; off >>= 1) s += __shfl_down(s, off);
    if (lane == 0) OUT[row] = s + sb0;
  }
}

// ---------------- launcher ----------------
extern "C" void kernel_launch(void* const* d_in, const int* in_sizes, int n_in,
                              void* d_out, int out_size, void* d_ws, size_t ws_size,
                              hipStream_t stream) {
  const float* x  = (const float*)d_in[0];   // [16384, 256]
  const float* c1 = (const float*)d_in[1];   // [512, 256, 16]
  const float* c2 = (const float*)d_in[2];   // [512, 512, 16]
  const float* c3 = (const float*)d_in[3];   // [1, 512, 16]
  const float* sw = (const float*)d_in[4];   // [1, 256]
  const float* sb = (const float*)d_in[5];   // [1]
  float* out = (float*)d_out;

  const int B = B_ROWS, IN = IN_DIM, H = H_DIM;

  char* ws = (char*)d_ws;
  size_t off = 0;
  auto alloc = [&](size_t bytes) -> void* {
    void* p = ws + off;
    off += (bytes + 255) & ~(size_t)255;
    return p;
  };
  _Float16* C1h = (_Float16*)alloc((size_t)H * IN * NB * 2);  //  4 MB
  _Float16* C2h = (_Float16*)alloc((size_t)H * H  * NB * 2);  //  8 MB
  float* H1 = (float*)alloc((size_t)B * H * 4);               // 32 MB
  float* H2 = (float*)alloc((size_t)B * H * 4);               // 32 MB
  float* ps  = (float*)alloc(128 * 512 * 4);                  // 256 KB
  float* ps2 = (float*)alloc(128 * 512 * 4);
  float* mu  = (float*)alloc(512 * 4);
  float* isd = (float*)alloc(512 * 4);

  // ---- prep: x-stats partials + coeff cvt in one dispatch ----
  prep_k<<<128 + 1024, 256, 0, stream>>>(c1, C1h, (size_t)H * IN * NB / 4,
                                         c2, C2h, (size_t)H * H * NB / 4,
                                         x, ps, ps2);
  stats_final_k<<<1, 256, 0, stream>>>(ps, ps2, 32, IN, B, mu, isd);

  // ---- layer 1 (C=256, K=4096); epilogue emits H1 column partials ----
  kan_gemm_fused<<<dim3(B / 128, 4), 256, 0, stream>>>(x, mu, isd, C1h, H1, ps, ps2, IN);
  stats_final_k<<<2, 256, 0, stream>>>(ps, ps2, 128, H, B, mu, isd);

  // ---- layer 2 (C=512, K=8192); epilogue emits H2 column partials ----
  kan_gemm_fused<<<dim3(B / 128, 4), 256, 0, stream>>>(H1, mu, isd, C2h, H2, ps, ps2, H);
  stats_final_k<<<2, 256, 0, stream>>>(ps, ps2, 128, H, B, mu, isd);

  // ---- layer 3 + skip (normalize fused) ----
  layer3_k<<<B / 16, 256, 0, stream>>>(H2, mu, isd, c3, x, sw, sb, out);
}